// Round 1
// baseline (457.938 us; speedup 1.0000x reference)
//
#include <hip/hip_runtime.h>
#include <cmath>

// Problem constants (from reference)
namespace {
constexpr int B   = 8;
constexpr int N   = 16384;
constexpr int C   = 16;
constexpr int P   = 2048;
constexpr int K   = 32;
constexpr int HID = 64;
constexpr int DM  = 64;
}

// Butterfly max-reduce step across k-lanes with value-halving.
// Before step: each lane holds 2*CNT values; after: CNT values.
// Upper lanes (lane&M) keep their upper half (d-offset += CNT).
template<int M, int CNT>
__device__ __forceinline__ void max_step(float* acc, int lane) {
    const bool up = (lane & M) != 0;
    #pragma unroll
    for (int i = 0; i < CNT; ++i) {
        float send = up ? acc[i] : acc[i + CNT];
        float recv = __shfl_xor(send, M, 64);
        float keep = up ? acc[i + CNT] : acc[i];
        acc[i] = fmaxf(keep, recv);
    }
}

__global__ __launch_bounds__(256) void apemb_kernel(
    const float* __restrict__ ans_feat,   // [B,N,C]
    const int*   __restrict__ group_idx,  // [B,P,K]
    const float* __restrict__ W1,         // [C,HID]
    const float* __restrict__ b1,         // [HID]
    const float* __restrict__ W2,         // [HID,DM]
    const float* __restrict__ b2,         // [DM]
    float* __restrict__ out)              // [B,P,DM]
{
    const int lane = threadIdx.x & 63;
    const int wid  = threadIdx.x >> 6;
    const int u    = blockIdx.x * 4 + wid;   // wave unit: 2 p's
    const int pp   = u * 2 + (lane >> 5);    // global row index b*P + p
    const int k    = lane & 31;
    const int bi   = pp >> 11;               // P = 2048

    // ---- gather: one neighbor row (16 floats) per lane ----
    const int idx = group_idx[pp * K + k];
    const float4* feat =
        (const float4*)(ans_feat + ((size_t)bi * N + (size_t)idx) * C);
    float a[C];
    #pragma unroll
    for (int q = 0; q < 4; ++q) {
        float4 f = feat[q];
        a[4*q+0] = f.x; a[4*q+1] = f.y; a[4*q+2] = f.z; a[4*q+3] = f.w;
    }

    // ---- GEMM1: h = a @ W1 + b1  (weights read with uniform addresses) ----
    float h[HID];
    #pragma unroll
    for (int j = 0; j < HID; ++j) h[j] = b1[j];
    #pragma unroll
    for (int c = 0; c < C; ++c) {
        const float av = a[c];
        #pragma unroll
        for (int j = 0; j < HID; ++j)
            h[j] = fmaf(av, W1[c * HID + j], h[j]);
    }

    // ---- exact GELU (erf form, matches approximate=False) ----
    #pragma unroll
    for (int j = 0; j < HID; ++j) {
        const float x = h[j];
        h[j] = 0.5f * x * (1.0f + erff(x * 0.70710678118654752f));
    }

    // ---- GEMM2: acc = h @ W2 + b2 (b2 is k-invariant: safe to add pre-max) ----
    float acc[DM];
    #pragma unroll
    for (int d = 0; d < DM; ++d) acc[d] = b2[d];
    #pragma unroll
    for (int j = 0; j < HID; ++j) {
        const float hv = h[j];
        #pragma unroll
        for (int d = 0; d < DM; ++d)
            acc[d] = fmaf(hv, W2[j * DM + d], acc[d]);
    }

    // ---- max over the 32 k-lanes of each half-wave (value-halving butterfly) ----
    max_step<1, 32>(acc, lane);
    max_step<2, 16>(acc, lane);
    max_step<4,  8>(acc, lane);
    max_step<8,  4>(acc, lane);
    max_step<16, 2>(acc, lane);

    // Lane (within its 32-group) now holds d0, d0+1 where:
    const int d0 = ((lane & 1)  << 5) | ((lane & 2)  << 3) | ((lane & 4) << 1)
                 | ((lane & 8)  >> 1) | ((lane & 16) >> 3);
    float2 r = make_float2(acc[0], acc[1]);
    *(float2*)(&out[(size_t)pp * DM + d0]) = r;
}

extern "C" void kernel_launch(void* const* d_in, const int* in_sizes, int n_in,
                              void* d_out, int out_size, void* d_ws, size_t ws_size,
                              hipStream_t stream) {
    const float* ans_feat  = (const float*)d_in[0];
    const int*   group_idx = (const int*)  d_in[1];
    const float* W1        = (const float*)d_in[2];
    const float* b1        = (const float*)d_in[3];
    const float* W2        = (const float*)d_in[4];
    const float* b2        = (const float*)d_in[5];
    float*       out       = (float*)d_out;

    // 8 p's per block (4 waves x 2 p's) -> B*P/8 = 2048 blocks
    dim3 grid(B * P / 8), block(256);
    apemb_kernel<<<grid, block, 0, stream>>>(ans_feat, group_idx, W1, b1, W2, b2, out);
}

// Round 10
// 114.725 us; speedup vs baseline: 3.9916x; 3.9916x over previous
//
#include <hip/hip_runtime.h>
#include <hip/hip_bf16.h>

namespace {
constexpr int B   = 8;
constexpr int N   = 16384;
constexpr int C   = 16;
constexpr int P   = 2048;
constexpr int K   = 32;
constexpr int HID = 64;
constexpr int DM  = 64;
constexpr int NP  = 8;                         // p's per wave
constexpr int WPB = 4;                         // waves per block
constexpr int NBLK = (B * P) / (NP * WPB);     // 512 blocks
}

typedef __attribute__((ext_vector_type(8)))  short s16x8;   // 8 bf16 (4 VGPRs)
typedef __attribute__((ext_vector_type(16))) float f32x16;  // MFMA 32x32 accum

static __device__ __forceinline__ ushort bfbits(float f) {
    __hip_bfloat16 h = __float2bfloat16(f);
    return *reinterpret_cast<ushort*>(&h);
}
static __device__ __forceinline__ uint pkbf(float lo, float hi) {
    return (uint)bfbits(lo) | ((uint)bfbits(hi) << 16);
}
static __device__ __forceinline__ s16x8 mk8(uint a, uint b, uint c, uint d) {
    union { uint u[4]; s16x8 s; } x;
    x.u[0] = a; x.u[1] = b; x.u[2] = c; x.u[3] = d;
    return x.s;
}

// tanh-form GELU (max |delta| vs exact erf ~3e-3; far under bf16 noise here)
static __device__ __forceinline__ float gelu(float x) {
    float u = 0.7978845608028654f * (x + 0.044715f * x * x * x);
    float e = exp2f(2.8853900817779268f * u);     // e^{2u}
    float t = 1.0f - 2.0f / (e + 1.0f);           // tanh(u)
    return 0.5f * x * (1.0f + t);
}

// value-halving butterfly max over lane bits (reduces over L = lane&31)
template<int M, int CNT>
__device__ __forceinline__ void max_step(float* acc, int lane) {
    const bool up = (lane & M) != 0;
    #pragma unroll
    for (int i = 0; i < CNT; ++i) {
        float send = up ? acc[i] : acc[i + CNT];
        float recv = __shfl_xor(send, M, 64);
        float keep = up ? acc[i + CNT] : acc[i];
        acc[i] = fmaxf(keep, recv);
    }
}

__global__ __launch_bounds__(256, 2) void apemb_mfma(
    const float* __restrict__ ans_feat,   // [B,N,C]
    const int*   __restrict__ gidx,       // [B,P,K] (staged as int32)
    const float* __restrict__ W1,         // [C,HID]
    const float* __restrict__ b1,         // [HID]
    const float* __restrict__ W2,         // [HID,DM]
    const float* __restrict__ b2,         // [DM]
    float* __restrict__ out)              // [B,P,DM]
{
    const int tid  = threadIdx.x;
    const int wid  = tid >> 6;
    const int lane = tid & 63;
    const int L    = lane & 31;   // instance r / matrix column
    const int bq   = lane >> 5;   // half-wave index

    // XCD swizzle: 64 consecutive blocks (= one batch) per XCD
    const int bid  = (int)blockIdx.x;
    const int lb   = (bid & 7) * (NBLK / 8) + (bid >> 3);
    const int wave = lb * WPB + wid;
    const int pbase = wave * NP;              // global row index b*P + p
    const int bi    = pbase >> 11;            // P = 2048
    const float* __restrict__ fb = ans_feat + (size_t)bi * N * C;

    // ---- persistent weight fragments (swapped-operand layout) ----
    // GEMM1 A = W1^T: lane holds W1[8*bq+j][32*m2+L], j=0..7
    s16x8 w1f[2];
    #pragma unroll
    for (int m2 = 0; m2 < 2; ++m2) {
        uint q[4];
        #pragma unroll
        for (int jp = 0; jp < 4; ++jp) {
            float lo = W1[(8 * bq + 2 * jp    ) * HID + 32 * m2 + L];
            float hi = W1[(8 * bq + 2 * jp + 1) * HID + 32 * m2 + L];
            q[jp] = pkbf(lo, hi);
        }
        w1f[m2] = mk8(q[0], q[1], q[2], q[3]);
    }

    // GEMM2 A = W2^T with sigma-permuted k-slots. Slot (bq,j) of fragment s
    // carries h = sigma_s(bq,j) = 32*(s>>1) + 8*(2*(s&1)+(j>>2)) + (j&3) + 4*bq
    // — chosen so the matching B-slot h-values are exactly the g-values this
    // lane already holds from GEMM1's accumulator (no cross-lane exchange).
    // Any shared k-slot relabeling cancels between A and B (ISA duality).
    s16x8 w2f[2][4];
    #pragma unroll
    for (int m3 = 0; m3 < 2; ++m3)
        #pragma unroll
        for (int s = 0; s < 4; ++s) {
            uint q[4];
            #pragma unroll
            for (int jp = 0; jp < 4; ++jp) {
                const int j0 = 2 * jp, j1 = 2 * jp + 1;
                const int h0 = 32 * (s >> 1) + 8 * (2 * (s & 1) + (j0 >> 2)) + (j0 & 3) + 4 * bq;
                const int h1 = 32 * (s >> 1) + 8 * (2 * (s & 1) + (j1 >> 2)) + (j1 & 3) + 4 * bq;
                q[jp] = pkbf(W2[h0 * DM + 32 * m3 + L], W2[h1 * DM + 32 * m3 + L]);
            }
            w2f[m3][s] = mk8(q[0], q[1], q[2], q[3]);
        }

    // b1 fragment matching H^T accum rows: h = 32*m2 + 8*(t>>2) + (t&3) + 4*bq
    float b1f[2][16];
    #pragma unroll
    for (int m2 = 0; m2 < 2; ++m2)
        #pragma unroll
        for (int t = 0; t < 16; ++t)
            b1f[m2][t] = b1[32 * m2 + 8 * (t >> 2) + (t & 3) + 4 * bq];

    // per-lane output channel after the butterfly (bitrev5 of L), + b2
    const int i5 = ((L & 1) << 4) | ((L & 2) << 2) | (L & 4) | ((L & 8) >> 2) | ((L & 16) >> 4);
    const int dl = 32 * (i5 >> 4) + 8 * ((i5 >> 2) & 3) + (i5 & 3) + 4 * bq;
    const float b2v = b2[dl];

    // ---- gather prefetch pipeline: idx 2 iters ahead, feat 1 ahead ----
    const int* gp = gidx + (size_t)pbase * K + L;
    int idxc = gp[0];
    const float* rp0 = fb + (size_t)idxc * C + 8 * bq;
    float4 curA = *(const float4*)rp0;
    float4 curB = *(const float4*)(rp0 + 4);
    int idxn = gp[K];

    #pragma unroll
    for (int it = 0; it < NP; ++it) {
        float4 nA = {}, nB = {};
        int idn2 = 0;
        if (it + 1 < NP) {
            const float* rp = fb + (size_t)idxn * C + 8 * bq;
            nA = *(const float4*)rp;
            nB = *(const float4*)(rp + 4);
        }
        if (it + 2 < NP) idn2 = gp[(it + 2) * K];

        // GEMM1 B-frag: feat[r=L][c=8*bq+j] — the gathered row-half itself
        s16x8 bf = mk8(pkbf(curA.x, curA.y), pkbf(curA.z, curA.w),
                       pkbf(curB.x, curB.y), pkbf(curB.z, curB.w));
        f32x16 zz = {};
        f32x16 a0 = __builtin_amdgcn_mfma_f32_32x32x16_bf16(w1f[0], bf, zz, 0, 0, 0);
        f32x16 a1 = __builtin_amdgcn_mfma_f32_32x32x16_bf16(w1f[1], bf, zz, 0, 0, 0);

        // bias + GELU (H^T accum: h = 32*m2 + 8*(t>>2) + (t&3) + 4*bq, r = L)
        float g[2][16];
        #pragma unroll
        for (int t = 0; t < 16; ++t) {
            g[0][t] = gelu(a0[t] + b1f[0][t]);
            g[1][t] = gelu(a1[t] + b1f[1][t]);
        }

        // GEMM2 B-frags via sigma: fragment s takes this lane's own quads
        // (m2 = s>>1, q = 2*(s&1)) and (m2, q+1) — no cross-lane exchange.
        s16x8 hf[4];
        #pragma unroll
        for (int s = 0; s < 4; ++s) {
            const int m2 = s >> 1;
            const int q0 = 2 * (s & 1), q1 = q0 + 1;
            hf[s] = mk8(pkbf(g[m2][4 * q0 + 0], g[m2][4 * q0 + 1]),
                        pkbf(g[m2][4 * q0 + 2], g[m2][4 * q0 + 3]),
                        pkbf(g[m2][4 * q1 + 0], g[m2][4 * q1 + 1]),
                        pkbf(g[m2][4 * q1 + 2], g[m2][4 * q1 + 3]));
        }

        // GEMM2: O^T[d][r] accum, d = 32*m3 + 8*(t>>2) + (t&3) + 4*bq
        f32x16 c0 = {}, c1 = {};
        #pragma unroll
        for (int s = 0; s < 4; ++s) {
            c0 = __builtin_amdgcn_mfma_f32_32x32x16_bf16(w2f[0][s], hf[s], c0, 0, 0, 0);
            c1 = __builtin_amdgcn_mfma_f32_32x32x16_bf16(w2f[1][s], hf[s], c1, 0, 0, 0);
        }

        // max-pool over r = L (32 lanes), value-halving butterfly
        float v[32];
        #pragma unroll
        for (int t = 0; t < 16; ++t) { v[t] = c0[t]; v[16 + t] = c1[t]; }
        max_step<1, 16>(v, lane);
        max_step<2,  8>(v, lane);
        max_step<4,  4>(v, lane);
        max_step<8,  2>(v, lane);
        max_step<16, 1>(v, lane);

        out[(size_t)(pbase + it) * DM + dl] = v[0] + b2v;

        curA = nA; curB = nB; idxc = idxn; idxn = idn2;
    }
}

extern "C" void kernel_launch(void* const* d_in, const int* in_sizes, int n_in,
                              void* d_out, int out_size, void* d_ws, size_t ws_size,
                              hipStream_t stream) {
    const float* ans_feat  = (const float*)d_in[0];
    const int*   group_idx = (const int*)  d_in[1];
    const float* W1        = (const float*)d_in[2];
    const float* b1        = (const float*)d_in[3];
    const float* W2        = (const float*)d_in[4];
    const float* b2        = (const float*)d_in[5];
    float*       out       = (float*)d_out;

    apemb_mfma<<<dim3(NBLK), dim3(256), 0, stream>>>(
        ans_feat, group_idx, W1, b1, W2, b2, out);
}